// Round 2
// baseline (336.335 us; speedup 1.0000x reference)
//
#include <hip/hip_runtime.h>
#include <stdint.h>

// R2: attention reads K / V^T straight from L2 (no LDS staging, zero barriers),
// 32 q-rows/wave, K reg double-buffer, MFMA row-sum, defer-max, log2 softmax.
// B=4 S=1024 D=1024 H=16 DK=64.

typedef unsigned short u16;
typedef short b16x8 __attribute__((ext_vector_type(8)));
typedef short b16x4 __attribute__((ext_vector_type(4)));
typedef float f32x4 __attribute__((ext_vector_type(4)));

__device__ __forceinline__ u16 f2bf(float f) {
  union { float f; uint32_t u; } v; v.f = f;
  uint32_t r = v.u + 0x7fffu + ((v.u >> 16) & 1u);
  return (u16)(r >> 16);
}

__device__ __forceinline__ f32x4 mfma16(b16x8 a, b16x8 b, f32x4 c) {
  return __builtin_amdgcn_mfma_f32_16x16x32_bf16(a, b, c, 0, 0, 0);
}

__device__ __forceinline__ void gld16(const void* g, void* l) {
  __builtin_amdgcn_global_load_lds(
      (const __attribute__((address_space(1))) void*)g,
      (__attribute__((address_space(3))) void*)l, 16, 0, 0);
}

__device__ __forceinline__ float ex2(float x) {
  float r; asm("v_exp_f32 %0, %1" : "=v"(r) : "v"(x)); return r;
}

__device__ __forceinline__ uint32_t cvtpk(float a, float b) {
  uint32_t r;
  asm("v_cvt_pk_bf16_f32 %0, %1, %2" : "=v"(r) : "v"(a), "v"(b));
  return r;
}

// ---------------- f32 -> bf16 converts ----------------
__global__ __launch_bounds__(256) void k_cvt2(const float* __restrict__ a,
                                              const float* __restrict__ b,
                                              u16* __restrict__ oa,
                                              u16* __restrict__ ob) {
  const float* in = blockIdx.y ? b : a;
  u16* out = blockIdx.y ? ob : oa;
  int i = (blockIdx.x * 256 + threadIdx.x) * 8;
  float4 x = *(const float4*)(in + i);
  float4 y = *(const float4*)(in + i + 4);
  b16x8 v;
  v[0] = (short)f2bf(x.x); v[1] = (short)f2bf(x.y);
  v[2] = (short)f2bf(x.z); v[3] = (short)f2bf(x.w);
  v[4] = (short)f2bf(y.x); v[5] = (short)f2bf(y.y);
  v[6] = (short)f2bf(y.z); v[7] = (short)f2bf(y.w);
  *(b16x8*)(out + i) = v;
}

// 6 weights in one launch; wq_* get softmax scale folded in (log2 domain).
__global__ __launch_bounds__(256) void k_cvtw(
    const float* __restrict__ w0, const float* __restrict__ w1,
    const float* __restrict__ w2, const float* __restrict__ w3,
    const float* __restrict__ w4, const float* __restrict__ w5,
    u16* __restrict__ wsc, u16* __restrict__ wcc) {
  const int idx = blockIdx.y;
  const float* in;
  switch (idx) {
    case 0: in = w0; break; case 1: in = w1; break; case 2: in = w2; break;
    case 3: in = w3; break; case 4: in = w4; break; default: in = w5; break;
  }
  u16* out = (idx < 3 ? wsc : wcc) + (idx % 3) * 1048576;
  const float sc = (idx % 3 == 0) ? 0.18033688f : 1.0f;  // 0.125*log2(e)
  int i = (blockIdx.x * 256 + threadIdx.x) * 8;
  float4 x = *(const float4*)(in + i);
  float4 y = *(const float4*)(in + i + 4);
  b16x8 v;
  v[0] = (short)f2bf(x.x * sc); v[1] = (short)f2bf(x.y * sc);
  v[2] = (short)f2bf(x.z * sc); v[3] = (short)f2bf(x.w * sc);
  v[4] = (short)f2bf(y.x * sc); v[5] = (short)f2bf(y.y * sc);
  v[6] = (short)f2bf(y.z * sc); v[7] = (short)f2bf(y.w * sc);
  *(b16x8*)(out + i) = v;
}

// ---------------- bf16 GEMM: C[M,N] = A[M,K] . B[N,K]^T ----------------
__global__ __launch_bounds__(256) void k_gemm_bt(const u16* __restrict__ A,
                                                 const u16* __restrict__ B,
                                                 u16* __restrict__ C,
                                                 int M, int N, int K) {
  __shared__ u16 Ab[128 * 32];
  __shared__ u16 Bb[128 * 32];
  const int tid = threadIdx.x;
  const int lane = tid & 63, w = tid >> 6;
  const int wr = w >> 1, wc = w & 1;
  const int q = lane & 15, hi = lane >> 4;
  // bijective XCD swizzle (nwg % 8 == 0 for all our grids)
  const int nwg = gridDim.x * gridDim.y;
  const int id = blockIdx.y * gridDim.x + blockIdx.x;
  const int swz = (id & 7) * (nwg >> 3) + (id >> 3);
  const int bx = swz % gridDim.x, by = swz / gridDim.x;
  const int mbase = by * 128, nbase = bx * 128;
  f32x4 acc[4][4] = {};
  for (int kb = 0; kb < K; kb += 32) {
    __syncthreads();
#pragma unroll
    for (int r = 0; r < 2; ++r) {
      int c = tid + 256 * r;
      int row = c >> 2, ch = c & 3;
      gld16(&A[(size_t)(mbase + row) * K + kb + ch * 8], &Ab[c * 8]);
      gld16(&B[(size_t)(nbase + row) * K + kb + ch * 8], &Bb[c * 8]);
    }
    __syncthreads();
    b16x8 af[4], bf[4];
#pragma unroll
    for (int mi = 0; mi < 4; ++mi)
      af[mi] = *(const b16x8*)&Ab[(wr * 64 + mi * 16 + q) * 32 + hi * 8];
#pragma unroll
    for (int ni = 0; ni < 4; ++ni)
      bf[ni] = *(const b16x8*)&Bb[(wc * 64 + ni * 16 + q) * 32 + hi * 8];
#pragma unroll
    for (int mi = 0; mi < 4; ++mi)
#pragma unroll
      for (int ni = 0; ni < 4; ++ni)
        acc[mi][ni] = mfma16(af[mi], bf[ni], acc[mi][ni]);
  }
#pragma unroll
  for (int mi = 0; mi < 4; ++mi)
#pragma unroll
    for (int ni = 0; ni < 4; ++ni) {
      int m0 = mbase + wr * 64 + mi * 16 + hi * 4;
      int n0 = nbase + wc * 64 + ni * 16 + q;
#pragma unroll
      for (int i = 0; i < 4; ++i)
        C[(size_t)(m0 + i) * N + n0] = f2bf(acc[mi][ni][i]);
    }
}

// ---------------- V transpose: in[b*1024+k][coff+h*64+d] -> out[bh][d][k] ----
__global__ __launch_bounds__(256) void k_vt(const u16* __restrict__ in, int sIn,
                                            int coff, u16* __restrict__ out) {
  __shared__ u16 T[64 * 72];
  const int tid = threadIdx.x;
  const int bh = blockIdx.y, kb = blockIdx.x * 64;
  const int b = bh >> 4, h = bh & 15;
  const int kvp = tid >> 3, ch = tid & 7;
  const u16* p = in + (size_t)(b * 1024 + kb + 2 * kvp) * sIn + coff + h * 64 + ch * 8;
  b16x8 r0 = *(const b16x8*)p;
  b16x8 r1 = *(const b16x8*)(p + sIn);
#pragma unroll
  for (int j = 0; j < 8; ++j) {
    int i = (j + ch) & 7;
    uint32_t pk = (uint32_t)(u16)r0[i] | ((uint32_t)(u16)r1[i] << 16);
    *(uint32_t*)&T[(ch * 8 + i) * 72 + 2 * kvp] = pk;
  }
  __syncthreads();
  const int d = tid >> 2, seg = tid & 3;
  b16x8 v0 = *(const b16x8*)&T[d * 72 + seg * 16];
  b16x8 v1 = *(const b16x8*)&T[d * 72 + seg * 16 + 8];
  u16* o = out + (size_t)(bh * 64 + d) * 1024 + kb + seg * 16;
  *(b16x8*)o = v0;
  *(b16x8*)(o + 8) = v1;
}

// ---------------- flash attention, direct-from-L2 ----------------
// 1 wave/block, 32 q-rows/wave (2 q-groups), KVBLK=64, no __syncthreads.
template <int CAUSAL, typename OT>
__global__ __launch_bounds__(64, 2) void attn2(
    const u16* __restrict__ Qp, int sQ,
    const u16* __restrict__ Kp, int sK, int koff,
    const u16* __restrict__ Vt,  // [bh][64][1024]
    OT* __restrict__ Op, int sO) {
  __shared__ u16 P[32 * 72];
  const int lane = threadIdx.x;
  const int q = lane & 15, hi = lane >> 4;
  // XCD swizzle: each XCD owns 8 consecutive bh (2MB K/V working set < 4MB L2)
  const int id = blockIdx.y * 32 + blockIdx.x;  // grid (32, 64)
  const int swz = (id & 7) * 256 + (id >> 3);
  const int qw = swz & 31, bh = swz >> 5;
  const int q0 = qw * 32;
  const size_t rowb = (size_t)(bh >> 4) * 1024;
  const int h = bh & 15;
  const int nt = CAUSAL ? (q0 >> 6) + 1 : 16;

  const u16* Kb = Kp + (rowb + q) * (size_t)sK + koff + h * 64 + hi * 8;
  const u16* Vb = Vt + (size_t)bh * 65536 + (size_t)q * 1024 + hi * 8;
  const u16* Qb = Qp + (rowb + q0 + q) * (size_t)sQ + h * 64 + hi * 8;

  b16x8 qf[2][2];
  qf[0][0] = *(const b16x8*)Qb;
  qf[0][1] = *(const b16x8*)(Qb + 32);
  qf[1][0] = *(const b16x8*)(Qb + (size_t)16 * sQ);
  qf[1][1] = *(const b16x8*)(Qb + (size_t)16 * sQ + 32);

  b16x8 ones;
#pragma unroll
  for (int i = 0; i < 8; ++i) ones[i] = (short)0x3F80;

  f32x4 acc[2][4] = {};
  f32x4 accl[2] = {};
  float m0 = -1e30f, m1 = -1e30f;

#define LOADK(KF, ti)                                                        \
  do {                                                                       \
    size_t _o = (size_t)((ti) * 64) * sK;                                    \
    KF[0] = *(const b16x8*)&Kb[_o];                                          \
    KF[1] = *(const b16x8*)&Kb[_o + 32];                                     \
    KF[2] = *(const b16x8*)&Kb[_o + (size_t)16 * sK];                        \
    KF[3] = *(const b16x8*)&Kb[_o + (size_t)16 * sK + 32];                   \
    KF[4] = *(const b16x8*)&Kb[_o + (size_t)32 * sK];                        \
    KF[5] = *(const b16x8*)&Kb[_o + (size_t)32 * sK + 32];                   \
    KF[6] = *(const b16x8*)&Kb[_o + (size_t)48 * sK];                        \
    KF[7] = *(const b16x8*)&Kb[_o + (size_t)48 * sK + 32];                   \
  } while (0)

  auto PROC = [&](const b16x8 (&kf)[8], int ti, bool domask) {
    const int kb = ti * 64;
    // V^T fragments for this tile (used ~300cy later -> latency hidden)
    b16x8 vf[8];
#pragma unroll
    for (int t = 0; t < 4; ++t) {
      vf[t * 2 + 0] = *(const b16x8*)&Vb[(size_t)t * 16384 + kb];
      vf[t * 2 + 1] = *(const b16x8*)&Vb[(size_t)t * 16384 + kb + 32];
    }
    // S^T = K . Q^T  (log2-domain scores; scale folded into wq)
    f32x4 st[2][4];
#pragma unroll
    for (int t = 0; t < 4; ++t)
#pragma unroll
      for (int g = 0; g < 2; ++g) {
        f32x4 z = {};
        z = mfma16(kf[t * 2], qf[g][0], z);
        st[g][t] = mfma16(kf[t * 2 + 1], qf[g][1], z);
      }
    // per-q max (4 lanes share a q: hi = lane>>4)
    float pm[2];
#pragma unroll
    for (int g = 0; g < 2; ++g) {
      float m = -INFINITY;
#pragma unroll
      for (int t = 0; t < 4; ++t)
#pragma unroll
        for (int i = 0; i < 4; ++i) {
          float v = st[g][t][i];
          if (CAUSAL && domask) {
            if (kb + 16 * t + 4 * hi + i > q0 + g * 16 + q) v = -INFINITY;
          }
          st[g][t][i] = v;
          m = fmaxf(m, v);
        }
      m = fmaxf(m, __shfl_xor(m, 16));
      m = fmaxf(m, __shfl_xor(m, 32));
      pm[g] = m;
    }
    // defer-max (T13): only rescale when max grew past threshold
    if (!__all(pm[0] <= m0 + 10.f && pm[1] <= m1 + 10.f)) {
      float n0 = fmaxf(m0, pm[0]), n1 = fmaxf(m1, pm[1]);
      float f0 = ex2(m0 - n0), f1 = ex2(m1 - n1);
#pragma unroll
      for (int t = 0; t < 4; ++t)
#pragma unroll
        for (int i = 0; i < 4; ++i) {
          acc[0][t][i] *= f0;
          acc[1][t][i] *= f1;
        }
#pragma unroll
      for (int i = 0; i < 4; ++i) { accl[0][i] *= f0; accl[1][i] *= f1; }
      m0 = n0; m1 = n1;
    }
    // P = 2^(st - m) -> bf16 pairs -> per-wave LDS (no barrier needed)
#pragma unroll
    for (int g = 0; g < 2; ++g) {
      const float mm = g ? m1 : m0;
#pragma unroll
      for (int t = 0; t < 4; ++t) {
        uint2 pw;
        pw.x = cvtpk(ex2(st[g][t][0] - mm), ex2(st[g][t][1] - mm));
        pw.y = cvtpk(ex2(st[g][t][2] - mm), ex2(st[g][t][3] - mm));
        *(uint2*)&P[(g * 16 + q) * 72 + 16 * t + 4 * hi] = pw;
      }
    }
    // O^T += V^T . P^T ; l += ones . P^T (row-sum via matrix pipe)
#pragma unroll
    for (int g = 0; g < 2; ++g) {
      b16x8 bp0 = *(const b16x8*)&P[(g * 16 + q) * 72 + hi * 8];
      b16x8 bp1 = *(const b16x8*)&P[(g * 16 + q) * 72 + 32 + hi * 8];
      accl[g] = mfma16(ones, bp0, accl[g]);
      accl[g] = mfma16(ones, bp1, accl[g]);
#pragma unroll
      for (int t = 0; t < 4; ++t) {
        acc[g][t] = mfma16(vf[t * 2], bp0, acc[g][t]);
        acc[g][t] = mfma16(vf[t * 2 + 1], bp1, acc[g][t]);
      }
    }
  };

  b16x8 kfA[8], kfB[8];
  LOADK(kfA, 0);
  int i = 0;
  while (true) {
    if (i == nt - 1) { PROC(kfA, i, CAUSAL != 0); break; }
    LOADK(kfB, i + 1);
    PROC(kfA, i, false);
    ++i;
    if (i == nt - 1) { PROC(kfB, i, CAUSAL != 0); break; }
    LOADK(kfA, i + 1);
    PROC(kfB, i, false);
    ++i;
  }
#undef LOADK

#pragma unroll
  for (int g = 0; g < 2; ++g) {
    const float inv = 1.0f / accl[g][0];
    const size_t ob = (rowb + q0 + g * 16 + q) * (size_t)sO + h * 64;
#pragma unroll
    for (int t = 0; t < 4; ++t) {
      const int d = 16 * t + 4 * hi;
      if constexpr (sizeof(OT) == 2) {
        b16x4 o;
        o[0] = (short)f2bf(acc[g][t][0] * inv);
        o[1] = (short)f2bf(acc[g][t][1] * inv);
        o[2] = (short)f2bf(acc[g][t][2] * inv);
        o[3] = (short)f2bf(acc[g][t][3] * inv);
        *(b16x4*)&((u16*)Op)[ob + d] = o;
      } else {
        float4 o = make_float4(acc[g][t][0] * inv, acc[g][t][1] * inv,
                               acc[g][t][2] * inv, acc[g][t][3] * inv);
        *(float4*)&((float*)Op)[ob + d] = o;
      }
    }
  }
}

extern "C" void kernel_launch(void* const* d_in, const int* in_sizes, int n_in,
                              void* d_out, int out_size, void* d_ws, size_t ws_size,
                              hipStream_t stream) {
  (void)in_sizes; (void)n_in; (void)out_size; (void)ws_size;
  const float* x   = (const float*)d_in[0];
  const float* enc = (const float*)d_in[1];
  const float* wqs = (const float*)d_in[4];
  const float* wks = (const float*)d_in[5];
  const float* wvs = (const float*)d_in[6];
  const float* wqc = (const float*)d_in[7];
  const float* wkc = (const float*)d_in[8];
  const float* wvc = (const float*)d_in[9];

  u16* ws   = (u16*)d_ws;
  u16* xb   = ws;                  // 4096x1024 ; reused as vtg1 after QKV1
  u16* encb = ws + 4194304;        // 4096x1024 ; reused as vtg2 after KV2
  u16* wsc  = ws + 8388608;        // 3x 1024x1024
  u16* wcc  = ws + 11534336;       // 3x 1024x1024
  u16* qkv1 = ws + 14680064;       // 4096x3072
  u16* x1b  = ws + 27262976;       // 4096x1024
  u16* q2   = ws + 31457280;       // 4096x1024
  u16* kv2  = ws + 35651584;       // 4096x2048

  k_cvt2<<<dim3(2048, 2), 256, 0, stream>>>(x, enc, xb, encb);
  k_cvtw<<<dim3(512, 6), 256, 0, stream>>>(wqs, wks, wvs, wqc, wkc, wvc,
                                           wsc, wcc);

  // layer 1
  k_gemm_bt<<<dim3(24, 32), 256, 0, stream>>>(xb, wsc, qkv1, 4096, 3072, 1024);
  k_vt<<<dim3(16, 64), 256, 0, stream>>>(qkv1, 3072, 2048, xb);  // V1^T -> xb
  attn2<1, u16><<<dim3(32, 64), 64, 0, stream>>>(
      qkv1, 3072, qkv1, 3072, 1024, xb, x1b, 1024);

  // layer 2
  k_gemm_bt<<<dim3(8, 32), 256, 0, stream>>>(x1b, wcc, q2, 4096, 1024, 1024);
  k_gemm_bt<<<dim3(16, 32), 256, 0, stream>>>(encb, wcc + 1048576, kv2,
                                              4096, 2048, 1024);
  k_vt<<<dim3(16, 64), 256, 0, stream>>>(kv2, 2048, 1024, encb);  // V2^T -> encb
  attn2<0, float><<<dim3(32, 64), 64, 0, stream>>>(
      q2, 1024, kv2, 2048, 0, encb, (float*)d_out, 1024);
}

// Round 5
// 268.780 us; speedup vs baseline: 1.2513x; 1.2513x over previous
//
#include <hip/hip_runtime.h>
#include <stdint.h>

// R5: attn4 = 4-wave dbuf LDS staging (GEMM-pinned mechanics) with ALL
// algebra pinned to the passing R1/R2 rounds: R1 swizzle (row&7),
// unpermuted QK^T, P via per-wave LDS round-trip, MFMA row-sum, defer-max,
// log2 softmax. B=4 S=1024 D=1024 H=16 DK=64.

typedef unsigned short u16;
typedef short b16x8 __attribute__((ext_vector_type(8)));
typedef short b16x4 __attribute__((ext_vector_type(4)));
typedef float f32x4 __attribute__((ext_vector_type(4)));

__device__ __forceinline__ u16 f2bf(float f) {
  union { float f; uint32_t u; } v; v.f = f;
  uint32_t r = v.u + 0x7fffu + ((v.u >> 16) & 1u);
  return (u16)(r >> 16);
}

__device__ __forceinline__ f32x4 mfma16(b16x8 a, b16x8 b, f32x4 c) {
  return __builtin_amdgcn_mfma_f32_16x16x32_bf16(a, b, c, 0, 0, 0);
}

__device__ __forceinline__ void gld16(const void* g, void* l) {
  __builtin_amdgcn_global_load_lds(
      (const __attribute__((address_space(1))) void*)g,
      (__attribute__((address_space(3))) void*)l, 16, 0, 0);
}

__device__ __forceinline__ float ex2(float x) {
  float r; asm("v_exp_f32 %0, %1" : "=v"(r) : "v"(x)); return r;
}

__device__ __forceinline__ uint32_t cvtpk(float a, float b) {
  uint32_t r;
  asm("v_cvt_pk_bf16_f32 %0, %1, %2" : "=v"(r) : "v"(a), "v"(b));
  return r;
}

// ---------------- f32 -> bf16 converts ----------------
__global__ __launch_bounds__(256) void k_cvt2(const float* __restrict__ a,
                                              const float* __restrict__ b,
                                              u16* __restrict__ oa,
                                              u16* __restrict__ ob) {
  const float* in = blockIdx.y ? b : a;
  u16* out = blockIdx.y ? ob : oa;
  int i = (blockIdx.x * 256 + threadIdx.x) * 8;
  float4 x = *(const float4*)(in + i);
  float4 y = *(const float4*)(in + i + 4);
  b16x8 v;
  v[0] = (short)f2bf(x.x); v[1] = (short)f2bf(x.y);
  v[2] = (short)f2bf(x.z); v[3] = (short)f2bf(x.w);
  v[4] = (short)f2bf(y.x); v[5] = (short)f2bf(y.y);
  v[6] = (short)f2bf(y.z); v[7] = (short)f2bf(y.w);
  *(b16x8*)(out + i) = v;
}

// 6 weights in one launch; wq_* get softmax scale folded in (log2 domain).
__global__ __launch_bounds__(256) void k_cvtw(
    const float* __restrict__ w0, const float* __restrict__ w1,
    const float* __restrict__ w2, const float* __restrict__ w3,
    const float* __restrict__ w4, const float* __restrict__ w5,
    u16* __restrict__ wsc, u16* __restrict__ wcc) {
  const int idx = blockIdx.y;
  const float* in;
  switch (idx) {
    case 0: in = w0; break; case 1: in = w1; break; case 2: in = w2; break;
    case 3: in = w3; break; case 4: in = w4; break; default: in = w5; break;
  }
  u16* out = (idx < 3 ? wsc : wcc) + (idx % 3) * 1048576;
  const float sc = (idx % 3 == 0) ? 0.18033688f : 1.0f;  // 0.125*log2(e)
  int i = (blockIdx.x * 256 + threadIdx.x) * 8;
  float4 x = *(const float4*)(in + i);
  float4 y = *(const float4*)(in + i + 4);
  b16x8 v;
  v[0] = (short)f2bf(x.x * sc); v[1] = (short)f2bf(x.y * sc);
  v[2] = (short)f2bf(x.z * sc); v[3] = (short)f2bf(x.w * sc);
  v[4] = (short)f2bf(y.x * sc); v[5] = (short)f2bf(y.y * sc);
  v[6] = (short)f2bf(y.z * sc); v[7] = (short)f2bf(y.w * sc);
  *(b16x8*)(out + i) = v;
}

// ---------------- bf16 GEMM: C[M,N] = A[M,K] . B[N,K]^T ----------------
__global__ __launch_bounds__(256) void k_gemm_bt(const u16* __restrict__ A,
                                                 const u16* __restrict__ B,
                                                 u16* __restrict__ C,
                                                 int M, int N, int K) {
  __shared__ u16 Ab[128 * 32];
  __shared__ u16 Bb[128 * 32];
  const int tid = threadIdx.x;
  const int lane = tid & 63, w = tid >> 6;
  const int wr = w >> 1, wc = w & 1;
  const int q = lane & 15, hi = lane >> 4;
  const int nwg = gridDim.x * gridDim.y;
  const int id = blockIdx.y * gridDim.x + blockIdx.x;
  const int swz = (id & 7) * (nwg >> 3) + (id >> 3);
  const int bx = swz % gridDim.x, by = swz / gridDim.x;
  const int mbase = by * 128, nbase = bx * 128;
  f32x4 acc[4][4] = {};
  for (int kb = 0; kb < K; kb += 32) {
    __syncthreads();
#pragma unroll
    for (int r = 0; r < 2; ++r) {
      int c = tid + 256 * r;
      int row = c >> 2, ch = c & 3;
      gld16(&A[(size_t)(mbase + row) * K + kb + ch * 8], &Ab[c * 8]);
      gld16(&B[(size_t)(nbase + row) * K + kb + ch * 8], &Bb[c * 8]);
    }
    __syncthreads();
    b16x8 af[4], bf[4];
#pragma unroll
    for (int mi = 0; mi < 4; ++mi)
      af[mi] = *(const b16x8*)&Ab[(wr * 64 + mi * 16 + q) * 32 + hi * 8];
#pragma unroll
    for (int ni = 0; ni < 4; ++ni)
      bf[ni] = *(const b16x8*)&Bb[(wc * 64 + ni * 16 + q) * 32 + hi * 8];
#pragma unroll
    for (int mi = 0; mi < 4; ++mi)
#pragma unroll
      for (int ni = 0; ni < 4; ++ni)
        acc[mi][ni] = mfma16(af[mi], bf[ni], acc[mi][ni]);
  }
#pragma unroll
  for (int mi = 0; mi < 4; ++mi)
#pragma unroll
    for (int ni = 0; ni < 4; ++ni) {
      int m0 = mbase + wr * 64 + mi * 16 + hi * 4;
      int n0 = nbase + wc * 64 + ni * 16 + q;
#pragma unroll
      for (int i = 0; i < 4; ++i)
        C[(size_t)(m0 + i) * N + n0] = f2bf(acc[mi][ni][i]);
    }
}

// ---------------- V transpose: in[b*1024+k][coff+h*64+d] -> out[bh][d][k] ----
__global__ __launch_bounds__(256) void k_vt(const u16* __restrict__ in, int sIn,
                                            int coff, u16* __restrict__ out) {
  __shared__ u16 T[64 * 72];
  const int tid = threadIdx.x;
  const int bh = blockIdx.y, kb = blockIdx.x * 64;
  const int b = bh >> 4, h = bh & 15;
  const int kvp = tid >> 3, ch = tid & 7;
  const u16* p = in + (size_t)(b * 1024 + kb + 2 * kvp) * sIn + coff + h * 64 + ch * 8;
  b16x8 r0 = *(const b16x8*)p;
  b16x8 r1 = *(const b16x8*)(p + sIn);
#pragma unroll
  for (int j = 0; j < 8; ++j) {
    int i = (j + ch) & 7;
    uint32_t pk = (uint32_t)(u16)r0[i] | ((uint32_t)(u16)r1[i] << 16);
    *(uint32_t*)&T[(ch * 8 + i) * 72 + 2 * kvp] = pk;
  }
  __syncthreads();
  const int d = tid >> 2, seg = tid & 3;
  b16x8 v0 = *(const b16x8*)&T[d * 72 + seg * 16];
  b16x8 v1 = *(const b16x8*)&T[d * 72 + seg * 16 + 8];
  u16* o = out + (size_t)(bh * 64 + d) * 1024 + kb + seg * 16;
  *(b16x8*)o = v0;
  *(b16x8*)(o + 8) = v1;
}

// ---------------- flash attention, 4-wave LDS-staged, pinned algebra ------
template <int CAUSAL, typename OT>
__global__ __launch_bounds__(256, 3) void attn4(
    const u16* __restrict__ Qp, int sQ,
    const u16* __restrict__ Kp, int sK, int koff,
    const u16* __restrict__ Vt,  // [bh][64 d][1024 kv]
    OT* __restrict__ Op, int sO) {
  __shared__ u16 Ksh[2][64 * 64];
  __shared__ u16 Vsh[2][64 * 64];
  __shared__ u16 Plds[4][32 * 72];
  const int tid = threadIdx.x;
  const int lane = tid & 63, w = tid >> 6;
  const int lq = lane & 15, hi = lane >> 4;

  // XCD-chunked; causal qb order paired (qb, 7-qb) for CU load balance.
  const int id = blockIdx.y * gridDim.x + blockIdx.x;  // grid (8, 64)
  const int xcd = id & 7, l = id >> 3;
  const int bh = xcd * 8 + (l >> 3);
  const int qb = (l < 32) ? (l & 7) : 7 - (l & 7);

  const size_t rowb = (size_t)(bh >> 4) * 1024;
  const int h = bh & 15;
  const int qw0 = qb * 128 + w * 32;  // this wave's first q row
  const int nt = CAUSAL ? 2 * qb + 2 : 16;

  const u16* Kbase = Kp + rowb * (size_t)sK + koff + h * 64;
  const u16* Vbase = Vt + (size_t)bh * 65536;
  const u16* Qb = Qp + (rowb + qw0 + lq) * (size_t)sQ + h * 64 + hi * 8;
  u16* Pw = &Plds[w][0];

  b16x8 qf[2][2];
  qf[0][0] = *(const b16x8*)Qb;
  qf[0][1] = *(const b16x8*)(Qb + 32);
  qf[1][0] = *(const b16x8*)(Qb + (size_t)16 * sQ);
  qf[1][1] = *(const b16x8*)(Qb + (size_t)16 * sQ + 32);

  b16x8 ones;
#pragma unroll
  for (int i = 0; i < 8; ++i) ones[i] = (short)0x3F80;

  const int key = lq & 7;  // read swizzle: row&7 with row=16t+lq -> lq&7

  f32x4 acc[2][4] = {};
  f32x4 accl[2] = {};
  float m0 = -1e30f, m1 = -1e30f;

  auto stage = [&](int bf, int kt2) {
    const int kb2 = kt2 * 64;
#pragma unroll
    for (int r = 0; r < 2; ++r) {
      int c = tid + 256 * r;
      int row = c >> 3, ch = c & 7;
      int sw = row & 7;  // R1-pinned swizzle
      gld16(&Kbase[(size_t)(kb2 + row) * sK + ((ch ^ sw) << 3)],
            &Ksh[bf][c * 8]);
      gld16(&Vbase[(size_t)row * 1024 + kb2 + ((ch ^ sw) << 3)],
            &Vsh[bf][c * 8]);
    }
  };

  stage(0, 0);
  for (int kt = 0; kt < nt; ++kt) {
    __syncthreads();  // drains own DMA (vmcnt) + all waves' LDS reads done
    if (kt + 1 < nt) stage((kt + 1) & 1, kt + 1);  // overlaps compute below
    const int kb = kt * 64;
    if (CAUSAL && kb > qw0 + 31) continue;  // wave fully masked this tile
    const u16* Kl = Ksh[kt & 1];
    const u16* Vl = Vsh[kt & 1];

    // S^T = K.Q^T (unpermuted R1/R2 mapping): st[g][t][i] <-> kv=kb+16t+4hi+i
    f32x4 st[2][4];
#pragma unroll
    for (int t = 0; t < 4; ++t) {
      const int row = 16 * t + lq;
      b16x8 k0 = *(const b16x8*)&Kl[row * 64 + ((hi ^ key) << 3)];
      b16x8 k1 = *(const b16x8*)&Kl[row * 64 + (((4 + hi) ^ key) << 3)];
      f32x4 z0 = {}, z1 = {};
      z0 = mfma16(k0, qf[0][0], z0);
      st[0][t] = mfma16(k1, qf[0][1], z0);
      z1 = mfma16(k0, qf[1][0], z1);
      st[1][t] = mfma16(k1, qf[1][1], z1);
    }

    // causal mask (boundary tiles only) + per-q max
    const bool dm = CAUSAL && (kb + 63 > qw0);
    float pm[2];
#pragma unroll
    for (int g = 0; g < 2; ++g) {
      if (dm) {
        const int qg = qw0 + g * 16 + lq;
#pragma unroll
        for (int t = 0; t < 4; ++t)
#pragma unroll
          for (int i = 0; i < 4; ++i)
            if (kb + 16 * t + 4 * hi + i > qg) st[g][t][i] = -INFINITY;
      }
      float m = -INFINITY;
#pragma unroll
      for (int t = 0; t < 4; ++t)
#pragma unroll
        for (int i = 0; i < 4; ++i) m = fmaxf(m, st[g][t][i]);
      m = fmaxf(m, __shfl_xor(m, 16));
      m = fmaxf(m, __shfl_xor(m, 32));
      pm[g] = m;
    }

    // defer-max (T13, log2 units)
    if (!__all((pm[0] <= m0 + 10.f) && (pm[1] <= m1 + 10.f))) {
      float n0 = fmaxf(m0, pm[0]), n1 = fmaxf(m1, pm[1]);
      float f0 = ex2(m0 - n0), f1 = ex2(m1 - n1);
#pragma unroll
      for (int t = 0; t < 4; ++t)
#pragma unroll
        for (int i = 0; i < 4; ++i) {
          acc[0][t][i] *= f0;
          acc[1][t][i] *= f1;
        }
#pragma unroll
      for (int i = 0; i < 4; ++i) { accl[0][i] *= f0; accl[1][i] *= f1; }
      m0 = n0; m1 = n1;
    }

    // P = 2^(st-m) -> per-wave LDS (R2-pinned layout; same-wave, no barrier)
#pragma unroll
    for (int g = 0; g < 2; ++g) {
      const float mm = g ? m1 : m0;
#pragma unroll
      for (int t = 0; t < 4; ++t) {
        uint2 pw;
        pw.x = cvtpk(ex2(st[g][t][0] - mm), ex2(st[g][t][1] - mm));
        pw.y = cvtpk(ex2(st[g][t][2] - mm), ex2(st[g][t][3] - mm));
        *(uint2*)&Pw[(g * 16 + lq) * 72 + 16 * t + 4 * hi] = pw;
      }
    }

    // V^T fragments from LDS (same swizzle family as K)
    b16x8 av0[4], av1[4];
#pragma unroll
    for (int t = 0; t < 4; ++t) {
      const int rv = 16 * t + lq;
      av0[t] = *(const b16x8*)&Vl[rv * 64 + ((hi ^ key) << 3)];
      av1[t] = *(const b16x8*)&Vl[rv * 64 + (((4 + hi) ^ key) << 3)];
    }

    // O^T += V^T.P^T ; l += ones.P^T (matrix-pipe row-sum)
#pragma unroll
    for (int g = 0; g < 2; ++g) {
      b16x8 bp0 = *(const b16x8*)&Pw[(g * 16 + lq) * 72 + hi * 8];
      b16x8 bp1 = *(const b16x8*)&Pw[(g * 16 + lq) * 72 + 32 + hi * 8];
      accl[g] = mfma16(ones, bp0, accl[g]);
      accl[g] = mfma16(ones, bp1, accl[g]);
#pragma unroll
      for (int t = 0; t < 4; ++t) {
        acc[g][t] = mfma16(av0[t], bp0, acc[g][t]);
        acc[g][t] = mfma16(av1[t], bp1, acc[g][t]);
      }
    }
  }

#pragma unroll
  for (int g = 0; g < 2; ++g) {
    const float inv = 1.0f / accl[g][0];
    const size_t ob = (rowb + qw0 + g * 16 + lq) * (size_t)sO + h * 64;
#pragma unroll
    for (int t = 0; t < 4; ++t) {
      const int d = 16 * t + 4 * hi;
      if constexpr (sizeof(OT) == 2) {
        b16x4 o;
        o[0] = (short)f2bf(acc[g][t][0] * inv);
        o[1] = (short)f2bf(acc[g][t][1] * inv);
        o[2] = (short)f2bf(acc[g][t][2] * inv);
        o[3] = (short)f2bf(acc[g][t][3] * inv);
        *(b16x4*)&((u16*)Op)[ob + d] = o;
      } else {
        float4 o = make_float4(acc[g][t][0] * inv, acc[g][t][1] * inv,
                               acc[g][t][2] * inv, acc[g][t][3] * inv);
        *(float4*)&((float*)Op)[ob + d] = o;
      }
    }
  }
}

extern "C" void kernel_launch(void* const* d_in, const int* in_sizes, int n_in,
                              void* d_out, int out_size, void* d_ws, size_t ws_size,
                              hipStream_t stream) {
  (void)in_sizes; (void)n_in; (void)out_size; (void)ws_size;
  const float* x   = (const float*)d_in[0];
  const float* enc = (const float*)d_in[1];
  const float* wqs = (const float*)d_in[4];
  const float* wks = (const float*)d_in[5];
  const float* wvs = (const float*)d_in[6];
  const float* wqc = (const float*)d_in[7];
  const float* wkc = (const float*)d_in[8];
  const float* wvc = (const float*)d_in[9];

  u16* ws   = (u16*)d_ws;
  u16* xb   = ws;                  // 4096x1024 ; reused as V1^T after QKV1
  u16* encb = ws + 4194304;        // 4096x1024 ; reused as V2^T after KV2
  u16* wsc  = ws + 8388608;        // 3x 1024x1024
  u16* wcc  = ws + 11534336;       // 3x 1024x1024
  u16* qkv1 = ws + 14680064;       // 4096x3072
  u16* x1b  = ws + 27262976;       // 4096x1024
  u16* q2   = ws + 31457280;       // 4096x1024
  u16* kv2  = ws + 35651584;       // 4096x2048

  k_cvt2<<<dim3(2048, 2), 256, 0, stream>>>(x, enc, xb, encb);
  k_cvtw<<<dim3(512, 6), 256, 0, stream>>>(wqs, wks, wvs, wqc, wkc, wvc,
                                           wsc, wcc);

  // layer 1
  k_gemm_bt<<<dim3(24, 32), 256, 0, stream>>>(xb, wsc, qkv1, 4096, 3072, 1024);
  k_vt<<<dim3(16, 64), 256, 0, stream>>>(qkv1, 3072, 2048, xb);  // V1^T
  attn4<1, u16><<<dim3(8, 64), 256, 0, stream>>>(
      qkv1, 3072, qkv1, 3072, 1024, xb, x1b, 1024);

  // layer 2
  k_gemm_bt<<<dim3(8, 32), 256, 0, stream>>>(x1b, wcc, q2, 4096, 1024, 1024);
  k_gemm_bt<<<dim3(16, 32), 256, 0, stream>>>(encb, wcc + 1048576, kv2,
                                              4096, 2048, 1024);
  k_vt<<<dim3(16, 64), 256, 0, stream>>>(kv2, 2048, 1024, encb);  // V2^T
  attn4<0, float><<<dim3(8, 64), 256, 0, stream>>>(
      q2, 1024, kv2, 2048, 0, encb, (float*)d_out, 1024);
}